// Round 10
// baseline (406.855 us; speedup 1.0000x reference)
//
#include <hip/hip_runtime.h>
#include <hip/hip_bf16.h>
#include <cstdint>
#include <cstddef>

#define B_    16
#define LQ    30
#define LD    1100
#define DIM   768
#define NH    12
#define DH_   64
#define WINSZ 11
#define WNUM  100
#define NSLOT 32              // 2 docs x 16 batches

typedef __attribute__((ext_vector_type(8))) short short8;
typedef __attribute__((ext_vector_type(4))) float f32x4;

__device__ __forceinline__ void gload_lds16(const void* g, void* l) {
  __builtin_amdgcn_global_load_lds(
      (const __attribute__((address_space(1))) void*)g,
      (__attribute__((address_space(3))) void*)l, 16, 0, 0);
}

// ---------------------------------------------------------------------------
// weights fp32 -> bf16 (once per launch)
// ---------------------------------------------------------------------------
__global__ __launch_bounds__(256) void wconv_kernel(const float* __restrict__ wa,
    const float* __restrict__ wb, __hip_bfloat16* __restrict__ oa,
    __hip_bfloat16* __restrict__ ob) {
  int i = (blockIdx.x * 256 + threadIdx.x) * 4;
  if (i >= DIM * DIM) return;
  float4 va = *reinterpret_cast<const float4*>(wa + i);
  float4 vb = *reinterpret_cast<const float4*>(wb + i);
  union { __hip_bfloat16 h[4]; uint2 u; } pa, pb;
  pa.h[0] = __float2bfloat16(va.x); pa.h[1] = __float2bfloat16(va.y);
  pa.h[2] = __float2bfloat16(va.z); pa.h[3] = __float2bfloat16(va.w);
  pb.h[0] = __float2bfloat16(vb.x); pb.h[1] = __float2bfloat16(vb.y);
  pb.h[2] = __float2bfloat16(vb.z); pb.h[3] = __float2bfloat16(vb.w);
  *reinterpret_cast<uint2*>(oa + i) = pa.u;
  *reinterpret_cast<uint2*>(ob + i) = pb.u;
}

// ---------------------------------------------------------------------------
// prep_q: Xq[row, e] = bf16( emb[q[row], e] * q_mask[row] * 0.125 )
// ---------------------------------------------------------------------------
__global__ __launch_bounds__(256) void prep_q_kernel(const int* __restrict__ q,
    const float* __restrict__ qmask, const float* __restrict__ emb,
    __hip_bfloat16* __restrict__ Xq) {
  int idx = blockIdx.x * 256 + threadIdx.x;        // 480 * 192 quads
  if (idx >= B_ * LQ * (DIM / 4)) return;
  int row = idx / (DIM / 4);
  int c4  = idx % (DIM / 4);
  float m = qmask[row] * 0.125f;
  float4 v = *reinterpret_cast<const float4*>(emb + (size_t)q[row] * DIM + c4 * 4);
  union { __hip_bfloat16 h[4]; uint2 u; } o;
  o.h[0] = __float2bfloat16(v.x * m); o.h[1] = __float2bfloat16(v.y * m);
  o.h[2] = __float2bfloat16(v.z * m); o.h[3] = __float2bfloat16(v.w * m);
  *reinterpret_cast<uint2*>(Xq + (size_t)row * DIM + c4 * 4) = o.u;
}

// ---------------------------------------------------------------------------
// prep_d (both docs): slot s = s0 + r/LD, doc = s>>4, b = s&15, t = r%LD.
// X[r,e] = bf16( (emb[tok,e]*sqrt(D) + pe[t,e]) * mask )   (pe if flag)
// ---------------------------------------------------------------------------
__global__ __launch_bounds__(256) void prep_d_kernel(const int* __restrict__ dpos,
    const int* __restrict__ dneg, const float* __restrict__ dpmask,
    const float* __restrict__ dnmask, const float* __restrict__ emb,
    const int* __restrict__ peflag, __hip_bfloat16* __restrict__ X,
    int s0, int rows) {
  int idx = blockIdx.x * 256 + threadIdx.x;        // rows * 192 quads
  if (idx >= rows * (DIM / 4)) return;
  int r  = idx / (DIM / 4);
  int c4 = idx % (DIM / 4);
  int s = s0 + r / LD;
  int t = r % LD;
  int doc = s >> 4, b = s & 15;
  const int*   di = doc ? dneg   : dpos;
  const float* dm = doc ? dnmask : dpmask;
  int grow = b * LD + t;
  float m = dm[grow];
  float4 v = *reinterpret_cast<const float4*>(emb + (size_t)di[grow] * DIM + c4 * 4);
  if (peflag[0]) {
    int i0 = c4 * 2;                               // pair indices i0, i0+1
    float d0 = expf(-0.023985261387f * (float)i0);
    float d1 = expf(-0.023985261387f * (float)(i0 + 1));
    float s0f, c0f, s1f, c1f;
    sincosf((float)t * d0, &s0f, &c0f);
    sincosf((float)t * d1, &s1f, &c1f);
    v.x = v.x * 27.712812921102035f + s0f;
    v.y = v.y * 27.712812921102035f + c0f;
    v.z = v.z * 27.712812921102035f + s1f;
    v.w = v.w * 27.712812921102035f + c1f;
  }
  union { __hip_bfloat16 h[4]; uint2 u; } o;
  o.h[0] = __float2bfloat16(v.x * m); o.h[1] = __float2bfloat16(v.y * m);
  o.h[2] = __float2bfloat16(v.z * m); o.h[3] = __float2bfloat16(v.w * m);
  *reinterpret_cast<uint2*>(X + (size_t)r * DIM + c4 * 4) = o.u;
}

// ---------------------------------------------------------------------------
// gemm_mfma: C[M,N] = A[M,K](bf16) @ Bt[N,K](bf16)^T, fp32 accum.
// 128x256 tile, BK=32, 512 thr = 8 waves (1Mx8N, per-wave 128x32 out,
// acc = 8x2 f32x4 = 64 regs -> 2 blocks/CU with 72 KB LDS: TLP x2 vs R9).
// 3 LDS bufs, stage-ahead-2, COUNTED vmcnt(3) once per K-step (never 0 in
// main loop), K-step split into the verified 2-phase interleave:
//   Phase 0: vmcnt(3)+barrier | read bq0,bq1+af0..3 | stage tile t+2 (3 gloads)
//            | lgkmcnt(0) | setprio | 16 MFMA (m0-3)
//   Phase 1: barrier | read af4..7 | lgkmcnt(0) | setprio | 16 MFMA (m4-7)
// RAW: per-wave vmcnt(3) retires its own tile-t loads; barrier makes them
//      visible block-wide. WAR: stage(t+2) hits buf (t-1)%3 whose readers
//      passed their lgkmcnt(0) before the phase-0 barrier of step t.
// T2 chunk-XOR swizzle both-sides (verified R7/R9: conflicts = 0); the
// read-side XOR term depends only on lane&15 (16-multiples vanish).
// Swapped-operand MFMA epilogue (verified R9): vectorized stores.
// DUAL-PROBLEM grid (verified R9): wgid >= tiles1 -> Q-GEMM (A2 -> C2 fp32).
// K mult of 32, K/32 >= 3. N mult of 256. A rows tile-padded; store r < M.
// ---------------------------------------------------------------------------
template <bool OUT_BF16>
__global__ __launch_bounds__(512, 4) void gemm_mfma(const __hip_bfloat16* __restrict__ A,
    const __hip_bfloat16* __restrict__ Bt, void* __restrict__ Cv,
    int M, int N, int K, int tilesX, int tiles1,
    const __hip_bfloat16* __restrict__ A2, float* __restrict__ C2, int M2) {
  extern __shared__ __hip_bfloat16 smem[];
  __hip_bfloat16* As = smem;                 // 3 bufs x 4096 elems (8 KB each)
  __hip_bfloat16* Bs = smem + 3 * 4096;      // 3 bufs x 8192 elems (16 KB each)

  const int nwg  = gridDim.x;
  const int orig = blockIdx.x;
  const int q8 = nwg >> 3, r8 = nwg & 7;
  const int xcd = orig & 7, pos = orig >> 3;
  const int wgid = (xcd < r8 ? xcd * (q8 + 1) : r8 * (q8 + 1) + (xcd - r8) * q8) + pos;

  const bool is2 = (wgid >= tiles1);
  const int  w2  = is2 ? (wgid - tiles1) : wgid;
  const int row0 = (w2 / tilesX) * 128;
  const int col0 = (w2 % tilesX) * 256;
  const __hip_bfloat16* Ap = is2 ? A2 : A;
  const int Mloc = is2 ? M2 : M;

  const int tid  = threadIdx.x;
  const int lane = tid & 63;
  const int wc   = tid >> 6;                 // wave = N-slice 0..7
  const int lo4 = lane & 15;
  const int hi4 = lane >> 4;

  // staging: thread covers row tid>>2 (A) / rows tid>>2 & 128+(tid>>2) (B),
  // chunk tid&3; pre-swizzled GLOBAL chunk (involution with read-side XOR):
  const int csrc = (tid & 3) ^ ((tid >> 3) & 3);
  const __hip_bfloat16* gA = Ap + (size_t)(row0 + (tid >> 2)) * K + csrc * 8;
  const __hip_bfloat16* gB = Bt + (size_t)(col0 + (tid >> 2)) * K + csrc * 8;

  // read-side swizzled chunk offset (same for all frags of this lane)
  const int coff = (hi4 ^ ((lo4 >> 1) & 3)) * 8;
  const int arow = lo4 * 32 + coff;                // + m*512 per A-frag
  const int brow = (wc * 32 + lo4) * 32 + coff;    // + n*512 per B-frag

  f32x4 acc[8][2] = {};

  auto STAGE = [&](int tt) {
    const int k0 = tt * 32;
    const int b3 = tt % 3;
    gload_lds16(gA + k0,                   As + b3 * 4096 + tid * 8);
    gload_lds16(gB + k0,                   Bs + b3 * 8192 + tid * 8);
    gload_lds16(gB + (size_t)128 * K + k0, Bs + b3 * 8192 + 4096 + tid * 8);
  };

#define MFMA2(MB)                                                       \
    acc[MB][0] = __builtin_amdgcn_mfma_f32_16x16x32_bf16(               \
        bq0, af0, acc[MB][0], 0, 0, 0);                                 \
    acc[MB][1] = __builtin_amdgcn_mfma_f32_16x16x32_bf16(               \
        bq1, af0, acc[MB][1], 0, 0, 0);                                 \
    acc[MB + 1][0] = __builtin_amdgcn_mfma_f32_16x16x32_bf16(           \
        bq0, af1, acc[MB + 1][0], 0, 0, 0);                             \
    acc[MB + 1][1] = __builtin_amdgcn_mfma_f32_16x16x32_bf16(           \
        bq1, af1, acc[MB + 1][1], 0, 0, 0);

#define STEP(tt, WAITN, DOSTAGE)                                        \
  {                                                                     \
    const int b3 = (tt) % 3;                                            \
    const __hip_bfloat16* Ab = As + b3 * 4096 + arow;                   \
    const __hip_bfloat16* Bb = Bs + b3 * 8192 + brow;                   \
    short8 bq0, bq1, af0, af1, af2, af3;                                \
    /* ---- phase 0 ---- */                                             \
    asm volatile("s_waitcnt vmcnt(" WAITN ")" ::: "memory");            \
    __builtin_amdgcn_s_barrier();                                       \
    __builtin_amdgcn_sched_barrier(0);                                  \
    bq0 = *reinterpret_cast<const short8*>(Bb);                         \
    bq1 = *reinterpret_cast<const short8*>(Bb + 512);                   \
    af0 = *reinterpret_cast<const short8*>(Ab);                         \
    af1 = *reinterpret_cast<const short8*>(Ab + 512);                   \
    af2 = *reinterpret_cast<const short8*>(Ab + 1024);                  \
    af3 = *reinterpret_cast<const short8*>(Ab + 1536);                  \
    if (DOSTAGE) STAGE((tt) + 2);                                       \
    asm volatile("s_waitcnt lgkmcnt(0)" ::: "memory");                  \
    __builtin_amdgcn_sched_barrier(0);                                  \
    __builtin_amdgcn_s_setprio(1);                                      \
    MFMA2(0)                                                            \
    { short8 t0 = af2, t1 = af3; af0 = t0; af1 = t1; }                  \
    MFMA2(2)                                                            \
    __builtin_amdgcn_s_setprio(0);                                      \
    /* ---- phase 1 ---- */                                             \
    __builtin_amdgcn_s_barrier();                                       \
    af0 = *reinterpret_cast<const short8*>(Ab + 2048);                  \
    af1 = *reinterpret_cast<const short8*>(Ab + 2560);                  \
    af2 = *reinterpret_cast<const short8*>(Ab + 3072);                  \
    af3 = *reinterpret_cast<const short8*>(Ab + 3584);                  \
    asm volatile("s_waitcnt lgkmcnt(0)" ::: "memory");                  \
    __builtin_amdgcn_sched_barrier(0);                                  \
    __builtin_amdgcn_s_setprio(1);                                      \
    MFMA2(4)                                                            \
    { short8 t0 = af2, t1 = af3; af0 = t0; af1 = t1; }                  \
    MFMA2(6)                                                            \
    __builtin_amdgcn_s_setprio(0);                                      \
  }

  const int nt = K / 32;            // 24 for K=768
  STAGE(0); STAGE(1);               // 6 loads in flight per wave
  for (int t = 0; t < nt - 2; ++t)
    STEP(t, "3", true)              // retire tile t; keep t+1, t+2 in flight
  STEP(nt - 2, "3", false)
  STEP(nt - 1, "0", false)
#undef STEP
#undef MFMA2

  // epilogue (swapped layout): lane holds C[row0 + m*16 + lo4]
  // [col0 + wc*32 + n*16 + hi4*4 + j] -> reg j walks consecutive columns.
#pragma unroll
  for (int m = 0; m < 8; ++m) {
    const int r = row0 + m * 16 + lo4;
    if (r < Mloc) {
#pragma unroll
      for (int n = 0; n < 2; ++n) {
        const int cb = col0 + wc * 32 + n * 16 + hi4 * 4;
        f32x4 v = acc[m][n];
        if (is2) {
          *reinterpret_cast<f32x4*>(C2 + (size_t)r * N + cb) = v;
        } else if constexpr (OUT_BF16) {
          union { __hip_bfloat16 h[4]; uint2 u; } p;
          p.h[0] = __float2bfloat16(v[0]); p.h[1] = __float2bfloat16(v[1]);
          p.h[2] = __float2bfloat16(v[2]); p.h[3] = __float2bfloat16(v[3]);
          *reinterpret_cast<uint2*>((__hip_bfloat16*)Cv + (size_t)r * N + cb) = p.u;
        } else {
          *reinterpret_cast<f32x4*>((float*)Cv + (size_t)r * N + cb) = v;
        }
      }
    }
  }
}

// ---------------------------------------------------------------------------
// attn: one block per (slot_local, w, h), 120 threads = 30 qi x 4 part.
// Q segment in registers from global (L2-hot); D staged in LDS fp32
// (broadcast float4 reads, conflict-free); shfl_xor partial-dot reduce.
// ---------------------------------------------------------------------------
__global__ __launch_bounds__(128) void attn_kernel(const float* __restrict__ Qs,
    const __hip_bfloat16* __restrict__ Y, __hip_bfloat16* __restrict__ ctx, int s0) {
  int blk = blockIdx.x;
  int h  = blk % NH;
  int w  = (blk / NH) % WNUM;
  int sl = blk / (NH * WNUM);
  int b  = (s0 + sl) & 15;          // batch index (doc-independent Q)

  __shared__ float Dl[WINSZ][DH_];

  const __hip_bfloat16* Yb = Y + ((size_t)(sl * LD + w * WINSZ)) * DIM + h * (WINSZ * DH_);
  const float* Qb = Qs + (size_t)b * (LQ * DIM) + h * (LQ * DH_);

  int tid = threadIdx.x;
  int qi = tid >> 2, part = tid & 3;

  if (tid < 88) {
    uint4 raw = *reinterpret_cast<const uint4*>(Yb + tid * 8);
    const __hip_bfloat16* hp = reinterpret_cast<const __hip_bfloat16*>(&raw);
    float* dst = &Dl[0][0] + tid * 8;
#pragma unroll
    for (int j = 0; j < 8; ++j) dst[j] = __bfloat162float(hp[j]);
  }

  float4 qreg[4];
#pragma unroll
  for (int j = 0; j < 4; ++j)
    qreg[j] = *reinterpret_cast<const float4*>(Qb + qi * DH_ + part * 16 + j * 4);
  __syncthreads();

  float dot[WINSZ];
#pragma unroll
  for (int k = 0; k < WINSZ; ++k) {
    const float4* dp = reinterpret_cast<const float4*>(&Dl[k][part * 16]);
    float s = 0.f;
#pragma unroll
    for (int j = 0; j < 4; ++j) {
      float4 dv = dp[j];
      s += qreg[j].x * dv.x + qreg[j].y * dv.y + qreg[j].z * dv.z + qreg[j].w * dv.w;
    }
    dot[k] = s;
  }
#pragma unroll
  for (int k = 0; k < WINSZ; ++k) {
    dot[k] += __shfl_xor(dot[k], 1);
    dot[k] += __shfl_xor(dot[k], 2);
  }
  float mx = -1e30f;
#pragma unroll
  for (int k = 0; k < WINSZ; ++k) mx = fmaxf(mx, dot[k]);
  float sum = 0.f;
#pragma unroll
  for (int k = 0; k < WINSZ; ++k) { dot[k] = expf(dot[k] - mx); sum += dot[k]; }
  float inv = 1.f / sum;

  float4 o[4] = {};
#pragma unroll
  for (int k = 0; k < WINSZ; ++k) {
    float pk = dot[k];
    const float4* dp = reinterpret_cast<const float4*>(&Dl[k][part * 16]);
#pragma unroll
    for (int j = 0; j < 4; ++j) {
      float4 dv = dp[j];
      o[j].x += pk * dv.x; o[j].y += pk * dv.y;
      o[j].z += pk * dv.z; o[j].w += pk * dv.w;
    }
  }
  union { __hip_bfloat16 hh[16]; uint4 v[2]; } pk;
#pragma unroll
  for (int j = 0; j < 4; ++j) {
    pk.hh[j * 4 + 0] = __float2bfloat16(o[j].x * inv);
    pk.hh[j * 4 + 1] = __float2bfloat16(o[j].y * inv);
    pk.hh[j * 4 + 2] = __float2bfloat16(o[j].z * inv);
    pk.hh[j * 4 + 3] = __float2bfloat16(o[j].w * inv);
  }
  __hip_bfloat16* op = ctx + (size_t)(sl * WNUM + w) * (LQ * DIM)
                     + h * (LQ * DH_) + qi * DH_ + part * 16;
  *reinterpret_cast<uint4*>(op)     = pk.v[0];
  *reinterpret_cast<uint4*>(op + 8) = pk.v[1];
}

// ---------------------------------------------------------------------------
extern "C" void kernel_launch(void* const* d_in, const int* in_sizes, int n_in,
                              void* d_out, int out_size, void* d_ws, size_t ws_size,
                              hipStream_t stream) {
  const int*   q      = (const int*)d_in[0];
  const int*   dpos   = (const int*)d_in[1];
  const int*   dneg   = (const int*)d_in[2];
  const float* qmask  = (const float*)d_in[3];
  const float* dpmask = (const float*)d_in[4];
  const float* dnmask = (const float*)d_in[5];
  const int*   peflag = (const int*)d_in[6];
  const float* emb    = (const float*)d_in[7];
  const float* Wlin   = (const float*)d_in[8];
  const float* Wout   = (const float*)d_in[9];
  float* out = (float*)d_out;

  const int LDS_BYTES = 3 * 4096 * 2 + 3 * 8192 * 2;   // 73728
  (void)hipFuncSetAttribute(reinterpret_cast<const void*>(&gemm_mfma<false>),
                            hipFuncAttributeMaxDynamicSharedMemorySize, LDS_BYTES);
  (void)hipFuncSetAttribute(reinterpret_cast<const void*>(&gemm_mfma<true>),
                            hipFuncAttributeMaxDynamicSharedMemorySize, LDS_BYTES);

  char* ws = (char*)d_ws;
  size_t off = 0;
  auto alloc = [&](size_t bytes) -> char* {
    char* p = ws + off; off += (bytes + 255) & ~(size_t)255; return p;
  };
  __hip_bfloat16* Xq   = (__hip_bfloat16*)alloc((size_t)512 * DIM * 2);  // 480 rows + tile pad
  float*          Qsc  = (float*)         alloc((size_t)B_ * LQ * DIM * 4);
  __hip_bfloat16* Wl16 = (__hip_bfloat16*)alloc((size_t)DIM * DIM * 2);
  __hip_bfloat16* Wo16 = (__hip_bfloat16*)alloc((size_t)DIM * DIM * 2);

  // slots per chunk: all 32 (both docs) if ws allows; else halve.
  // buffers tile-padded (+128 rows) so gemm A-overreads stay in-bounds.
  int SC = NSLOT;
  while (SC > 1) {
    size_t need = off
        + ((size_t)SC * LD + 128) * DIM * 2 * 2                 // X + Y
        + ((size_t)SC * WNUM * LQ + 128) * DIM * 2 + (1u << 20);// ctx
    if (need <= ws_size) break;
    SC >>= 1;
  }
  __hip_bfloat16* X   = (__hip_bfloat16*)alloc(((size_t)SC * LD + 128) * DIM * 2);
  __hip_bfloat16* Y   = (__hip_bfloat16*)alloc(((size_t)SC * LD + 128) * DIM * 2);
  __hip_bfloat16* ctx = (__hip_bfloat16*)alloc(((size_t)SC * WNUM * LQ + 128) * DIM * 2);

  wconv_kernel<<<(DIM * DIM / 4 + 255) / 256, 256, 0, stream>>>(Wlin, Wout, Wl16, Wo16);
  prep_q_kernel<<<(B_ * LQ * (DIM / 4) + 255) / 256, 256, 0, stream>>>(q, qmask, emb, Xq);

  const int tilesX = DIM / 256;                        // 3 (BN=256)
  const int qTiles = tilesX * ((B_ * LQ + 127) / 128); // 12 (Q-problem blocks)

  for (int s0 = 0; s0 < NSLOT; s0 += SC) {
    const int rowsX = SC * LD;           // 35200 at SC=32 (275 M-tiles exact)
    const int rowsC = SC * WNUM * LQ;    // 96000 at SC=32 (750 M-tiles exact)
    prep_d_kernel<<<(rowsX * (DIM / 4) + 255) / 256, 256, 0, stream>>>(
        dpos, dneg, dpmask, dnmask, emb, peflag, X, s0, rowsX);
    {
      // GEMM1 (+ fused Q-GEMM tail blocks on the first chunk)
      int tiles1 = tilesX * ((rowsX + 127) / 128);
      int t2 = (s0 == 0) ? qTiles : 0;
      gemm_mfma<true><<<tiles1 + t2, 512, LDS_BYTES, stream>>>(
          X, Wl16, Y, rowsX, DIM, DIM, tilesX, tiles1, Xq, Qsc, B_ * LQ);
    }
    attn_kernel<<<SC * WNUM * NH, 120, 0, stream>>>(Qsc, Y, ctx, s0);
    {
      int tiles1 = tilesX * ((rowsC + 127) / 128);
      gemm_mfma<false><<<tiles1, 512, LDS_BYTES, stream>>>(
          ctx, Wo16, out + (size_t)s0 * WNUM * LQ * DIM, rowsC, DIM, DIM,
          tilesX, tiles1, nullptr, nullptr, 0);
    }
  }
}

// Round 11
// 392.731 us; speedup vs baseline: 1.0360x; 1.0360x over previous
//
#include <hip/hip_runtime.h>
#include <hip/hip_bf16.h>
#include <cstdint>
#include <cstddef>

#define B_    16
#define LQ    30
#define LD    1100
#define DIM   768
#define NH    12
#define DH_   64
#define WINSZ 11
#define WNUM  100
#define NSLOT 32              // 2 docs x 16 batches

typedef __attribute__((ext_vector_type(8))) short short8;
typedef __attribute__((ext_vector_type(4))) float f32x4;

__device__ __forceinline__ void gload_lds16(const void* g, void* l) {
  __builtin_amdgcn_global_load_lds(
      (const __attribute__((address_space(1))) void*)g,
      (__attribute__((address_space(3))) void*)l, 16, 0, 0);
}

// ---------------------------------------------------------------------------
// weights fp32 -> bf16 (once per launch)
// ---------------------------------------------------------------------------
__global__ __launch_bounds__(256) void wconv_kernel(const float* __restrict__ wa,
    const float* __restrict__ wb, __hip_bfloat16* __restrict__ oa,
    __hip_bfloat16* __restrict__ ob) {
  int i = (blockIdx.x * 256 + threadIdx.x) * 4;
  if (i >= DIM * DIM) return;
  float4 va = *reinterpret_cast<const float4*>(wa + i);
  float4 vb = *reinterpret_cast<const float4*>(wb + i);
  union { __hip_bfloat16 h[4]; uint2 u; } pa, pb;
  pa.h[0] = __float2bfloat16(va.x); pa.h[1] = __float2bfloat16(va.y);
  pa.h[2] = __float2bfloat16(va.z); pa.h[3] = __float2bfloat16(va.w);
  pb.h[0] = __float2bfloat16(vb.x); pb.h[1] = __float2bfloat16(vb.y);
  pb.h[2] = __float2bfloat16(vb.z); pb.h[3] = __float2bfloat16(vb.w);
  *reinterpret_cast<uint2*>(oa + i) = pa.u;
  *reinterpret_cast<uint2*>(ob + i) = pb.u;
}

// ---------------------------------------------------------------------------
// pe_table: pe[t, e] for t in [0,LD), e in [0,DIM). BIT-IDENTICAL float
// expressions to the previous in-prep_d computation (expf/sincosf), computed
// once instead of 32x per launch.
// ---------------------------------------------------------------------------
__global__ __launch_bounds__(256) void pe_kernel(float* __restrict__ pe) {
  int idx = blockIdx.x * 256 + threadIdx.x;        // LD * 192 quads
  if (idx >= LD * (DIM / 4)) return;
  int t  = idx / (DIM / 4);
  int c4 = idx % (DIM / 4);
  int i0 = c4 * 2;
  float d0 = expf(-0.023985261387f * (float)i0);
  float d1 = expf(-0.023985261387f * (float)(i0 + 1));
  float s0f, c0f, s1f, c1f;
  sincosf((float)t * d0, &s0f, &c0f);
  sincosf((float)t * d1, &s1f, &c1f);
  *reinterpret_cast<float4*>(pe + (size_t)t * DIM + c4 * 4) =
      make_float4(s0f, c0f, s1f, c1f);
}

// ---------------------------------------------------------------------------
// prep_q: Xq[row, e] = bf16( emb[q[row], e] * q_mask[row] * 0.125 )
// ---------------------------------------------------------------------------
__global__ __launch_bounds__(256) void prep_q_kernel(const int* __restrict__ q,
    const float* __restrict__ qmask, const float* __restrict__ emb,
    __hip_bfloat16* __restrict__ Xq) {
  int idx = blockIdx.x * 256 + threadIdx.x;        // 480 * 192 quads
  if (idx >= B_ * LQ * (DIM / 4)) return;
  int row = idx / (DIM / 4);
  int c4  = idx % (DIM / 4);
  float m = qmask[row] * 0.125f;
  float4 v = *reinterpret_cast<const float4*>(emb + (size_t)q[row] * DIM + c4 * 4);
  union { __hip_bfloat16 h[4]; uint2 u; } o;
  o.h[0] = __float2bfloat16(v.x * m); o.h[1] = __float2bfloat16(v.y * m);
  o.h[2] = __float2bfloat16(v.z * m); o.h[3] = __float2bfloat16(v.w * m);
  *reinterpret_cast<uint2*>(Xq + (size_t)row * DIM + c4 * 4) = o.u;
}

// ---------------------------------------------------------------------------
// prep_d (both docs): slot s = s0 + r/LD, doc = s>>4, b = s&15, t = r%LD.
// X[r,e] = bf16( (emb[tok,e]*sqrt(D) + pe[t,e]) * mask )   (pe if flag)
// PE from the precomputed table (bit-identical to trig-in-kernel).
// ---------------------------------------------------------------------------
__global__ __launch_bounds__(256) void prep_d_kernel(const int* __restrict__ dpos,
    const int* __restrict__ dneg, const float* __restrict__ dpmask,
    const float* __restrict__ dnmask, const float* __restrict__ emb,
    const int* __restrict__ peflag, const float* __restrict__ pe,
    __hip_bfloat16* __restrict__ X, int s0, int rows) {
  int idx = blockIdx.x * 256 + threadIdx.x;        // rows * 192 quads
  if (idx >= rows * (DIM / 4)) return;
  int r  = idx / (DIM / 4);
  int c4 = idx % (DIM / 4);
  int s = s0 + r / LD;
  int t = r % LD;
  int doc = s >> 4, b = s & 15;
  const int*   di = doc ? dneg   : dpos;
  const float* dm = doc ? dnmask : dpmask;
  int grow = b * LD + t;
  float m = dm[grow];
  float4 v = *reinterpret_cast<const float4*>(emb + (size_t)di[grow] * DIM + c4 * 4);
  if (peflag[0]) {
    float4 p = *reinterpret_cast<const float4*>(pe + (size_t)t * DIM + c4 * 4);
    v.x = v.x * 27.712812921102035f + p.x;
    v.y = v.y * 27.712812921102035f + p.y;
    v.z = v.z * 27.712812921102035f + p.z;
    v.w = v.w * 27.712812921102035f + p.w;
  }
  union { __hip_bfloat16 h[4]; uint2 u; } o;
  o.h[0] = __float2bfloat16(v.x * m); o.h[1] = __float2bfloat16(v.y * m);
  o.h[2] = __float2bfloat16(v.z * m); o.h[3] = __float2bfloat16(v.w * m);
  *reinterpret_cast<uint2*>(X + (size_t)r * DIM + c4 * 4) = o.u;
}

// ---------------------------------------------------------------------------
// gemm_mfma: C[M,N] = A[M,K](bf16) @ Bt[N,K](bf16)^T, fp32 accum.
// EXACT R9 structure (verified best of the shape family):
// 256x256 tile, BK=32, 512 thr = 8 waves (2Mx4N), 4 LDS bufs, stage-ahead-3,
// counted vmcnt(8), 2-phase interleave, chunk-XOR swizzle both-sides
// (conflicts measured 0), swapped-operand MFMA -> vectorized stores,
// dual-problem grid (Q-GEMM folded into GEMM1's launch).
// NEW: fp32 main-output store is NON-TEMPORAL (out is never re-read; keeps
// ctx/Wout streams resident in L2/L3).
// ---------------------------------------------------------------------------
template <bool OUT_BF16>
__global__ __launch_bounds__(512, 2) void gemm_mfma(const __hip_bfloat16* __restrict__ A,
    const __hip_bfloat16* __restrict__ Bt, void* __restrict__ Cv,
    int M, int N, int K, int tilesX, int tiles1,
    const __hip_bfloat16* __restrict__ A2, float* __restrict__ C2, int M2) {
  extern __shared__ __hip_bfloat16 smem[];
  __hip_bfloat16* As = smem;                 // 4 bufs x 8192 elems (16 KB each)
  __hip_bfloat16* Bs = smem + 4 * 8192;

  const int nwg  = gridDim.x;
  const int orig = blockIdx.x;
  const int q8 = nwg >> 3, r8 = nwg & 7;
  const int xcd = orig & 7, pos = orig >> 3;
  const int wgid = (xcd < r8 ? xcd * (q8 + 1) : r8 * (q8 + 1) + (xcd - r8) * q8) + pos;

  const bool is2 = (wgid >= tiles1);
  const int  w2  = is2 ? (wgid - tiles1) : wgid;
  const int row0 = (w2 / tilesX) * 256;
  const int col0 = (w2 % tilesX) * 256;
  const __hip_bfloat16* Ap = is2 ? A2 : A;
  const int Mloc = is2 ? M2 : M;

  const int tid  = threadIdx.x;
  const int lane = tid & 63;
  const int wave = tid >> 6;
  const int wr = wave >> 2, wc = wave & 3;     // 2 x 4 waves
  const int lo4 = lane & 15;
  const int hi4 = lane >> 4;

  const int csrc = (tid & 3) ^ ((tid >> 3) & 3);
  const __hip_bfloat16* gA = Ap + (size_t)(row0 + (tid >> 2)) * K + csrc * 8;
  const __hip_bfloat16* gB = Bt + (size_t)(col0 + (tid >> 2)) * K + csrc * 8;

  const int coff = ((hi4 ^ ((lo4 >> 1) & 3)) * 8);
  const int arow = (wr * 128 + lo4) * 32 + coff;   // +m*512 per A-frag
  const int brow = (wc * 64  + lo4) * 32 + coff;   // +n*512 per B-frag

  f32x4 acc[8][4] = {};

  auto STAGE = [&](int tt) {
    const int k0 = tt * 32;
    const int lo = (tt & 3) * 8192;
    gload_lds16(gA + k0,                   As + lo + tid * 8);
    gload_lds16(gA + (size_t)128 * K + k0, As + lo + 4096 + tid * 8);
    gload_lds16(gB + k0,                   Bs + lo + tid * 8);
    gload_lds16(gB + (size_t)128 * K + k0, Bs + lo + 4096 + tid * 8);
  };

#define MFMA4(MB)                                                       \
    _Pragma("unroll")                                                   \
    for (int n = 0; n < 4; ++n)                                         \
      acc[MB][n] = __builtin_amdgcn_mfma_f32_16x16x32_bf16(             \
          bq[n], af0, acc[MB][n], 0, 0, 0);                             \
    _Pragma("unroll")                                                   \
    for (int n = 0; n < 4; ++n)                                         \
      acc[MB + 1][n] = __builtin_amdgcn_mfma_f32_16x16x32_bf16(         \
          bq[n], af1, acc[MB + 1][n], 0, 0, 0);

#define STEP(tt, WAITN, DOSTAGE)                                        \
  {                                                                     \
    const int lo = ((tt) & 3) * 8192;                                   \
    const int so = (((tt) + 3) & 3) * 8192;                             \
    const int k0s = ((tt) + 3) * 32;                                    \
    const __hip_bfloat16* Ab = As + lo + arow;                          \
    const __hip_bfloat16* Bb = Bs + lo + brow;                          \
    short8 bq[4], af0, af1, af2, af3;                                   \
    /* ---- phase 0 ---- */                                             \
    asm volatile("s_waitcnt vmcnt(" WAITN ")" ::: "memory");            \
    __builtin_amdgcn_s_barrier();                                       \
    __builtin_amdgcn_sched_barrier(0);                                  \
    bq[0] = *reinterpret_cast<const short8*>(Bb);                       \
    bq[1] = *reinterpret_cast<const short8*>(Bb + 512);                 \
    bq[2] = *reinterpret_cast<const short8*>(Bb + 1024);                \
    bq[3] = *reinterpret_cast<const short8*>(Bb + 1536);                \
    af0 = *reinterpret_cast<const short8*>(Ab);                         \
    af1 = *reinterpret_cast<const short8*>(Ab + 512);                   \
    af2 = *reinterpret_cast<const short8*>(Ab + 1024);                  \
    af3 = *reinterpret_cast<const short8*>(Ab + 1536);                  \
    if (DOSTAGE) {                                                      \
      gload_lds16(gA + k0s,                   As + so + tid * 8);       \
      gload_lds16(gA + (size_t)128 * K + k0s, As + so + 4096 + tid * 8);\
    }                                                                   \
    asm volatile("s_waitcnt lgkmcnt(0)" ::: "memory");                  \
    __builtin_amdgcn_sched_barrier(0);                                  \
    __builtin_amdgcn_s_setprio(1);                                      \
    MFMA4(0)                                                            \
    { short8 t0 = af2, t1 = af3; af0 = t0; af1 = t1; }                  \
    MFMA4(2)                                                            \
    __builtin_amdgcn_s_setprio(0);                                      \
    /* ---- phase 1 ---- */                                             \
    __builtin_amdgcn_s_barrier();                                       \
    af0 = *reinterpret_cast<const short8*>(Ab + 2048);                  \
    af1 = *reinterpret_cast<const short8*>(Ab + 2560);                  \
    af2 = *reinterpret_cast<const short8*>(Ab + 3072);                  \
    af3 = *reinterpret_cast<const short8*>(Ab + 3584);                  \
    if (DOSTAGE) {                                                      \
      gload_lds16(gB + k0s,                   Bs + so + tid * 8);       \
      gload_lds16(gB + (size_t)128 * K + k0s, Bs + so + 4096 + tid * 8);\
    }                                                                   \
    asm volatile("s_waitcnt lgkmcnt(0)" ::: "memory");                  \
    __builtin_amdgcn_sched_barrier(0);                                  \
    __builtin_amdgcn_s_setprio(1);                                      \
    MFMA4(4)                                                            \
    { short8 t0 = af2, t1 = af3; af0 = t0; af1 = t1; }                  \
    MFMA4(6)                                                            \
    __builtin_amdgcn_s_setprio(0);                                      \
  }

  const int nt = K / 32;            // 24 for K=768
  STAGE(0); STAGE(1); STAGE(2);     // 12 loads in flight
  for (int t = 0; t < nt - 3; ++t)
    STEP(t, "8", true)              // retire tile t; keep t+1..t+3 in flight
  STEP(nt - 3, "8", false)
  STEP(nt - 2, "4", false)
  STEP(nt - 1, "0", false)
#undef STEP
#undef MFMA4

  // epilogue (swapped layout): lane holds C[row = ..+lo4][col = ..+hi4*4+j]
#pragma unroll
  for (int m = 0; m < 8; ++m) {
    const int r = row0 + wr * 128 + m * 16 + lo4;
    if (r < Mloc) {
#pragma unroll
      for (int n = 0; n < 4; ++n) {
        const int cb = col0 + wc * 64 + n * 16 + hi4 * 4;
        f32x4 v = acc[m][n];
        if (is2) {
          *reinterpret_cast<f32x4*>(C2 + (size_t)r * N + cb) = v;
        } else if constexpr (OUT_BF16) {
          union { __hip_bfloat16 h[4]; uint2 u; } p;
          p.h[0] = __float2bfloat16(v[0]); p.h[1] = __float2bfloat16(v[1]);
          p.h[2] = __float2bfloat16(v[2]); p.h[3] = __float2bfloat16(v[3]);
          *reinterpret_cast<uint2*>((__hip_bfloat16*)Cv + (size_t)r * N + cb) = p.u;
        } else {
          // final output: never re-read -> non-temporal (bypass L2 pollution)
          __builtin_nontemporal_store(
              v, reinterpret_cast<f32x4*>((float*)Cv + (size_t)r * N + cb));
        }
      }
    }
  }
}

// ---------------------------------------------------------------------------
// attn: one block per (slot_local, w, h), 120 threads = 30 qi x 4 part.
// Q segment in registers from global (L2-hot); D staged in LDS fp32
// (broadcast float4 reads, conflict-free); shfl_xor partial-dot reduce.
// ---------------------------------------------------------------------------
__global__ __launch_bounds__(128) void attn_kernel(const float* __restrict__ Qs,
    const __hip_bfloat16* __restrict__ Y, __hip_bfloat16* __restrict__ ctx, int s0) {
  int blk = blockIdx.x;
  int h  = blk % NH;
  int w  = (blk / NH) % WNUM;
  int sl = blk / (NH * WNUM);
  int b  = (s0 + sl) & 15;          // batch index (doc-independent Q)

  __shared__ float Dl[WINSZ][DH_];

  const __hip_bfloat16* Yb = Y + ((size_t)(sl * LD + w * WINSZ)) * DIM + h * (WINSZ * DH_);
  const float* Qb = Qs + (size_t)b * (LQ * DIM) + h * (LQ * DH_);

  int tid = threadIdx.x;
  int qi = tid >> 2, part = tid & 3;

  if (tid < 88) {
    uint4 raw = *reinterpret_cast<const uint4*>(Yb + tid * 8);
    const __hip_bfloat16* hp = reinterpret_cast<const __hip_bfloat16*>(&raw);
    float* dst = &Dl[0][0] + tid * 8;
#pragma unroll
    for (int j = 0; j < 8; ++j) dst[j] = __bfloat162float(hp[j]);
  }

  float4 qreg[4];
#pragma unroll
  for (int j = 0; j < 4; ++j)
    qreg[j] = *reinterpret_cast<const float4*>(Qb + qi * DH_ + part * 16 + j * 4);
  __syncthreads();

  float dot[WINSZ];
#pragma unroll
  for (int k = 0; k < WINSZ; ++k) {
    const float4* dp = reinterpret_cast<const float4*>(&Dl[k][part * 16]);
    float s = 0.f;
#pragma unroll
    for (int j = 0; j < 4; ++j) {
      float4 dv = dp[j];
      s += qreg[j].x * dv.x + qreg[j].y * dv.y + qreg[j].z * dv.z + qreg[j].w * dv.w;
    }
    dot[k] = s;
  }
#pragma unroll
  for (int k = 0; k < WINSZ; ++k) {
    dot[k] += __shfl_xor(dot[k], 1);
    dot[k] += __shfl_xor(dot[k], 2);
  }
  float mx = -1e30f;
#pragma unroll
  for (int k = 0; k < WINSZ; ++k) mx = fmaxf(mx, dot[k]);
  float sum = 0.f;
#pragma unroll
  for (int k = 0; k < WINSZ; ++k) { dot[k] = expf(dot[k] - mx); sum += dot[k]; }
  float inv = 1.f / sum;

  float4 o[4] = {};
#pragma unroll
  for (int k = 0; k < WINSZ; ++k) {
    float pk = dot[k];
    const float4* dp = reinterpret_cast<const float4*>(&Dl[k][part * 16]);
#pragma unroll
    for (int j = 0; j < 4; ++j) {
      float4 dv = dp[j];
      o[j].x += pk * dv.x; o[j].y += pk * dv.y;
      o[j].z += pk * dv.z; o[j].w += pk * dv.w;
    }
  }
  union { __hip_bfloat16 hh[16]; uint4 v[2]; } pk;
#pragma unroll
  for (int j = 0; j < 4; ++j) {
    pk.hh[j * 4 + 0] = __float2bfloat16(o[j].x * inv);
    pk.hh[j * 4 + 1] = __float2bfloat16(o[j].y * inv);
    pk.hh[j * 4 + 2] = __float2bfloat16(o[j].z * inv);
    pk.hh[j * 4 + 3] = __float2bfloat16(o[j].w * inv);
  }
  __hip_bfloat16* op = ctx + (size_t)(sl * WNUM + w) * (LQ * DIM)
                     + h * (LQ * DH_) + qi * DH_ + part * 16;
  *reinterpret_cast<uint4*>(op)     = pk.v[0];
  *reinterpret_cast<uint4*>(op + 8) = pk.v[1];
}

// ---------------------------------------------------------------------------
extern "C" void kernel_launch(void* const* d_in, const int* in_sizes, int n_in,
                              void* d_out, int out_size, void* d_ws, size_t ws_size,
                              hipStream_t stream) {
  const int*   q      = (const int*)d_in[0];
  const int*   dpos   = (const int*)d_in[1];
  const int*   dneg   = (const int*)d_in[2];
  const float* qmask  = (const float*)d_in[3];
  const float* dpmask = (const float*)d_in[4];
  const float* dnmask = (const float*)d_in[5];
  const int*   peflag = (const int*)d_in[6];
  const float* emb    = (const float*)d_in[7];
  const float* Wlin   = (const float*)d_in[8];
  const float* Wout   = (const float*)d_in[9];
  float* out = (float*)d_out;

  // allow 128 KB dynamic LDS (first call is uncaptured; attribute persists)
  (void)hipFuncSetAttribute(reinterpret_cast<const void*>(&gemm_mfma<false>),
                            hipFuncAttributeMaxDynamicSharedMemorySize, 131072);
  (void)hipFuncSetAttribute(reinterpret_cast<const void*>(&gemm_mfma<true>),
                            hipFuncAttributeMaxDynamicSharedMemorySize, 131072);

  char* ws = (char*)d_ws;
  size_t off = 0;
  auto alloc = [&](size_t bytes) -> char* {
    char* p = ws + off; off += (bytes + 255) & ~(size_t)255; return p;
  };
  __hip_bfloat16* Xq   = (__hip_bfloat16*)alloc((size_t)512 * DIM * 2);  // 480 rows + tile pad
  float*          Qsc  = (float*)         alloc((size_t)B_ * LQ * DIM * 4);
  __hip_bfloat16* Wl16 = (__hip_bfloat16*)alloc((size_t)DIM * DIM * 2);
  __hip_bfloat16* Wo16 = (__hip_bfloat16*)alloc((size_t)DIM * DIM * 2);
  float*          PE   = (float*)         alloc((size_t)LD * DIM * 4);   // 3.4 MB

  // slots per chunk: all 32 (both docs) if ws allows; else halve.
  // buffers tile-padded (+256 rows) so gemm A-overreads stay in-bounds.
  int SC = NSLOT;
  while (SC > 1) {
    size_t need = off
        + ((size_t)SC * LD + 256) * DIM * 2 * 2                 // X + Y
        + ((size_t)SC * WNUM * LQ + 256) * DIM * 2 + (1u << 20);// ctx
    if (need <= ws_size) break;
    SC >>= 1;
  }
  __hip_bfloat16* X   = (__hip_bfloat16*)alloc(((size_t)SC * LD + 256) * DIM * 2);
  __hip_bfloat16* Y   = (__hip_bfloat16*)alloc(((size_t)SC * LD + 256) * DIM * 2);
  __hip_bfloat16* ctx = (__hip_bfloat16*)alloc(((size_t)SC * WNUM * LQ + 256) * DIM * 2);

  wconv_kernel<<<(DIM * DIM / 4 + 255) / 256, 256, 0, stream>>>(Wlin, Wout, Wl16, Wo16);
  pe_kernel<<<(LD * (DIM / 4) + 255) / 256, 256, 0, stream>>>(PE);
  prep_q_kernel<<<(B_ * LQ * (DIM / 4) + 255) / 256, 256, 0, stream>>>(q, qmask, emb, Xq);

  const int tilesX = DIM / 256;                       // 3
  const int qTiles = tilesX * ((B_ * LQ + 255) / 256);// 6 (Q-problem blocks)

  for (int s0 = 0; s0 < NSLOT; s0 += SC) {
    const int rowsX = SC * LD;           // 35200 at SC=32
    const int rowsC = SC * WNUM * LQ;    // 96000 at SC=32
    prep_d_kernel<<<(rowsX * (DIM / 4) + 255) / 256, 256, 0, stream>>>(
        dpos, dneg, dpmask, dnmask, emb, peflag, PE, X, s0, rowsX);
    {
      // GEMM1 (+ fused Q-GEMM tail blocks on the first chunk)
      int tiles1 = tilesX * ((rowsX + 255) / 256);
      int t2 = (s0 == 0) ? qTiles : 0;
      gemm_mfma<true><<<tiles1 + t2, 512, 131072, stream>>>(
          X, Wl16, Y, rowsX, DIM, DIM, tilesX, tiles1, Xq, Qsc, B_ * LQ);
    }
    attn_kernel<<<SC * WNUM * NH, 120, 0, stream>>>(Qsc, Y, ctx, s0);
    {
      int tiles1 = tilesX * ((rowsC + 255) / 256);
      gemm_mfma<false><<<tiles1, 512, 131072, stream>>>(
          ctx, Wo16, out + (size_t)s0 * WNUM * LQ * DIM, rowsC, DIM, DIM,
          tilesX, tiles1, nullptr, nullptr, 0);
    }
  }
}

// Round 12
// 374.424 us; speedup vs baseline: 1.0866x; 1.0489x over previous
//
#include <hip/hip_runtime.h>
#include <hip/hip_bf16.h>
#include <cstdint>
#include <cstddef>

#define B_    16
#define LQ    30
#define LD    1100
#define DIM   768
#define NH    12
#define DH_   64
#define WINSZ 11
#define WNUM  100
#define NSLOT 32              // 2 docs x 16 batches

typedef __attribute__((ext_vector_type(8))) short short8;
typedef __attribute__((ext_vector_type(4))) float f32x4;

__device__ __forceinline__ void gload_lds16(const void* g, void* l) {
  __builtin_amdgcn_global_load_lds(
      (const __attribute__((address_space(1))) void*)g,
      (__attribute__((address_space(3))) void*)l, 16, 0, 0);
}

// ---------------------------------------------------------------------------
// weights fp32 -> bf16 (once per launch)
// ---------------------------------------------------------------------------
__global__ __launch_bounds__(256) void wconv_kernel(const float* __restrict__ wa,
    const float* __restrict__ wb, __hip_bfloat16* __restrict__ oa,
    __hip_bfloat16* __restrict__ ob) {
  int i = (blockIdx.x * 256 + threadIdx.x) * 4;
  if (i >= DIM * DIM) return;
  float4 va = *reinterpret_cast<const float4*>(wa + i);
  float4 vb = *reinterpret_cast<const float4*>(wb + i);
  union { __hip_bfloat16 h[4]; uint2 u; } pa, pb;
  pa.h[0] = __float2bfloat16(va.x); pa.h[1] = __float2bfloat16(va.y);
  pa.h[2] = __float2bfloat16(va.z); pa.h[3] = __float2bfloat16(va.w);
  pb.h[0] = __float2bfloat16(vb.x); pb.h[1] = __float2bfloat16(vb.y);
  pb.h[2] = __float2bfloat16(vb.z); pb.h[3] = __float2bfloat16(vb.w);
  *reinterpret_cast<uint2*>(oa + i) = pa.u;
  *reinterpret_cast<uint2*>(ob + i) = pb.u;
}

// ---------------------------------------------------------------------------
// pe_table: pe[t, e], bit-identical float expressions to the in-kernel trig.
// ---------------------------------------------------------------------------
__global__ __launch_bounds__(256) void pe_kernel(float* __restrict__ pe) {
  int idx = blockIdx.x * 256 + threadIdx.x;        // LD * 192 quads
  if (idx >= LD * (DIM / 4)) return;
  int t  = idx / (DIM / 4);
  int c4 = idx % (DIM / 4);
  int i0 = c4 * 2;
  float d0 = expf(-0.023985261387f * (float)i0);
  float d1 = expf(-0.023985261387f * (float)(i0 + 1));
  float s0f, c0f, s1f, c1f;
  sincosf((float)t * d0, &s0f, &c0f);
  sincosf((float)t * d1, &s1f, &c1f);
  *reinterpret_cast<float4*>(pe + (size_t)t * DIM + c4 * 4) =
      make_float4(s0f, c0f, s1f, c1f);
}

// ---------------------------------------------------------------------------
// prep_q: Xq[row, e] = bf16( emb[q[row], e] * q_mask[row] * 0.125 )
// ---------------------------------------------------------------------------
__global__ __launch_bounds__(256) void prep_q_kernel(const int* __restrict__ q,
    const float* __restrict__ qmask, const float* __restrict__ emb,
    __hip_bfloat16* __restrict__ Xq) {
  int idx = blockIdx.x * 256 + threadIdx.x;        // 480 * 192 quads
  if (idx >= B_ * LQ * (DIM / 4)) return;
  int row = idx / (DIM / 4);
  int c4  = idx % (DIM / 4);
  float m = qmask[row] * 0.125f;
  float4 v = *reinterpret_cast<const float4*>(emb + (size_t)q[row] * DIM + c4 * 4);
  union { __hip_bfloat16 h[4]; uint2 u; } o;
  o.h[0] = __float2bfloat16(v.x * m); o.h[1] = __float2bfloat16(v.y * m);
  o.h[2] = __float2bfloat16(v.z * m); o.h[3] = __float2bfloat16(v.w * m);
  *reinterpret_cast<uint2*>(Xq + (size_t)row * DIM + c4 * 4) = o.u;
}

// ---------------------------------------------------------------------------
// prep_d (both docs): slot s = s0 + r/LD, doc = s>>4, b = s&15, t = r%LD.
// ---------------------------------------------------------------------------
__global__ __launch_bounds__(256) void prep_d_kernel(const int* __restrict__ dpos,
    const int* __restrict__ dneg, const float* __restrict__ dpmask,
    const float* __restrict__ dnmask, const float* __restrict__ emb,
    const int* __restrict__ peflag, const float* __restrict__ pe,
    __hip_bfloat16* __restrict__ X, int s0, int rows) {
  int idx = blockIdx.x * 256 + threadIdx.x;        // rows * 192 quads
  if (idx >= rows * (DIM / 4)) return;
  int r  = idx / (DIM / 4);
  int c4 = idx % (DIM / 4);
  int s = s0 + r / LD;
  int t = r % LD;
  int doc = s >> 4, b = s & 15;
  const int*   di = doc ? dneg   : dpos;
  const float* dm = doc ? dnmask : dpmask;
  int grow = b * LD + t;
  float m = dm[grow];
  float4 v = *reinterpret_cast<const float4*>(emb + (size_t)di[grow] * DIM + c4 * 4);
  if (peflag[0]) {
    float4 p = *reinterpret_cast<const float4*>(pe + (size_t)t * DIM + c4 * 4);
    v.x = v.x * 27.712812921102035f + p.x;
    v.y = v.y * 27.712812921102035f + p.y;
    v.z = v.z * 27.712812921102035f + p.z;
    v.w = v.w * 27.712812921102035f + p.w;
  }
  union { __hip_bfloat16 h[4]; uint2 u; } o;
  o.h[0] = __float2bfloat16(v.x * m); o.h[1] = __float2bfloat16(v.y * m);
  o.h[2] = __float2bfloat16(v.z * m); o.h[3] = __float2bfloat16(v.w * m);
  *reinterpret_cast<uint2*>(X + (size_t)r * DIM + c4 * 4) = o.u;
}

// ---------------------------------------------------------------------------
// gemm_mfma: C[M,N] = A[M,K](bf16) @ Bt[N,K](bf16)^T, fp32 accum. K == 768.
// 256x256 tile, 512 thr = 8 waves (2Mx4N), per-wave 128x64 out.
// m201-template 8-PHASE schedule: BK=64 K-tiles, 2 tiles per iteration,
// 2 LDS slots per operand (128 KB total). Per phase: barrier | ds-read
// subtile (B-all+A-pair at P0/P4, A-pair else) | stage ONE half-tile
// (2 global_load_lds) | lgkmcnt(0) | setprio | 16 MFMA.
// Counted vmcnt(4) only at P0/P4 (never 0 in main loop); stage plan:
//   P0:Alo(t+1) P1:Ahi(t+1) P2:Blo(t+2) P3:Bhi(t+2)
//   P4:Alo(t+2) P5:Ahi(t+2) P6:Blo(t+3) P7:Bhi(t+3)
// WAR: every half is staged >=1 phase after its last reader phase (entry
// barriers + in-phase lgkmcnt(0) make prior-phase reads complete).
// RAW: vmcnt(4) retires exactly {B(t),A(t)} at P0 / {B,A(t+1)} at P4.
// T2 unit-XOR swizzle both-sides (unit x ^= row&7; pre-swizzled global src).
// Swapped-operand MFMA epilogue -> vectorized stores; dual-problem Q-fusion.
// ---------------------------------------------------------------------------
template <bool OUT_BF16>
__global__ __launch_bounds__(512, 2) void gemm_mfma(const __hip_bfloat16* __restrict__ A,
    const __hip_bfloat16* __restrict__ Bt, void* __restrict__ Cv,
    int M, int N, int K, int tilesX, int tiles1,
    const __hip_bfloat16* __restrict__ A2, float* __restrict__ C2, int M2) {
  extern __shared__ __hip_bfloat16 smem[];
  // A: slot0 [0,16384), slot1 [16384,32768); B: 32768 + slot*16384.

  const int nwg  = gridDim.x;
  const int orig = blockIdx.x;
  const int q8 = nwg >> 3, r8 = nwg & 7;
  const int xcd = orig & 7, pos = orig >> 3;
  const int wgid = (xcd < r8 ? xcd * (q8 + 1) : r8 * (q8 + 1) + (xcd - r8) * q8) + pos;

  const bool is2 = (wgid >= tiles1);
  const int  w2  = is2 ? (wgid - tiles1) : wgid;
  const int row0 = (w2 / tilesX) * 256;
  const int col0 = (w2 % tilesX) * 256;
  const __hip_bfloat16* Ap = is2 ? A2 : A;
  const int Mloc = is2 ? M2 : M;

  const int tid  = threadIdx.x;
  const int lane = tid & 63;
  const int wave = tid >> 6;
  const int wr = wave >> 2, wc = wave & 3;     // 2 x 4 waves
  const int lo4 = lane & 15;
  const int hi4 = lane >> 4;

  // ---- staging constants (pre-swizzled global source; LDS dest linear) ----
  // half-tile = 128 rows x 64 K = 1024 16B-units; thread covers units
  // u0 = tid, u1 = 512+tid. LDS unit (row, x) holds global chunk x^(row&7).
  const int u0 = tid,        r0s = u0 >> 3, x0s = u0 & 7;
  const int u1 = 512 + tid,  r1s = u1 >> 3, x1s = u1 & 7;
  const int soff0 = r0s * K + ((x0s ^ (r0s & 7)) * 8);
  const int soff1 = r1s * K + ((x1s ^ (r1s & 7)) * 8);
  const int wvoff = wave * 512;                // dest elems (wave-uniform)
  const __hip_bfloat16* gA = Ap + (size_t)row0 * K;
  const __hip_bfloat16* gB = Bt + (size_t)col0 * K;

#define STAGE_HALF(PTR, KOFF, HALF, SLOTBASE)                            \
  gload_lds16((PTR) + (size_t)(HALF) * (128 * 768) + (KOFF) + soff0,    \
              smem + (SLOTBASE) + (HALF) * 8192 + wvoff);               \
  gload_lds16((PTR) + (size_t)(HALF) * (128 * 768) + (KOFF) + soff1,    \
              smem + (SLOTBASE) + (HALF) * 8192 + 4096 + wvoff);

  // ---- fragment read constants (read-side of the same swizzle) ----
  const int rA = (wr * 128 + lo4) * 64;        // + m*1024
  const int rB = (wc * 64  + lo4) * 64;        // + n*1024
  const int xk0 = ((0 + hi4) ^ (lo4 & 7)) * 8; // kk = 0
  const int xk1 = ((4 + hi4) ^ (lo4 & 7)) * 8; // kk = 1

#define LDA(S, MM, XK) (*reinterpret_cast<const short8*>(smem + (S) * 16384 + rA + (MM) * 1024 + (XK)))
#define LDB(S, NN, XK) (*reinterpret_cast<const short8*>(smem + 32768 + (S) * 16384 + rB + (NN) * 1024 + (XK)))

  f32x4 acc[8][4] = {};
  short8 bf[4][2], aa0, aa1, aa2, aa3;

#define MM4(MMI, KK, AREG)                                                         \
  acc[MMI][0] = __builtin_amdgcn_mfma_f32_16x16x32_bf16(bf[0][KK], AREG, acc[MMI][0], 0, 0, 0); \
  acc[MMI][1] = __builtin_amdgcn_mfma_f32_16x16x32_bf16(bf[1][KK], AREG, acc[MMI][1], 0, 0, 0); \
  acc[MMI][2] = __builtin_amdgcn_mfma_f32_16x16x32_bf16(bf[2][KK], AREG, acc[MMI][2], 0, 0, 0); \
  acc[MMI][3] = __builtin_amdgcn_mfma_f32_16x16x32_bf16(bf[3][KK], AREG, acc[MMI][3], 0, 0, 0);
#define MFMA_PAIR(MA, MB) MM4(MA, 0, aa0) MM4(MB, 0, aa1) MM4(MA, 1, aa2) MM4(MB, 1, aa3)

#define LDB8(S)                                                          \
  bf[0][0] = LDB(S, 0, xk0); bf[1][0] = LDB(S, 1, xk0);                  \
  bf[2][0] = LDB(S, 2, xk0); bf[3][0] = LDB(S, 3, xk0);                  \
  bf[0][1] = LDB(S, 0, xk1); bf[1][1] = LDB(S, 1, xk1);                  \
  bf[2][1] = LDB(S, 2, xk1); bf[3][1] = LDB(S, 3, xk1);
#define LDA4(S, MA, MB)                                                  \
  aa0 = LDA(S, MA, xk0); aa1 = LDA(S, MB, xk0);                          \
  aa2 = LDA(S, MA, xk1); aa3 = LDA(S, MB, xk1);

#define BARR  { __builtin_amdgcn_s_barrier(); __builtin_amdgcn_sched_barrier(0); }
#define VMW(NLIT) asm volatile("s_waitcnt vmcnt(" NLIT ")" ::: "memory");
#define SYNC_MFMA { asm volatile("s_waitcnt lgkmcnt(0)" ::: "memory");   \
                    __builtin_amdgcn_sched_barrier(0);                   \
                    __builtin_amdgcn_s_setprio(1); }
#define END_MFMA  __builtin_amdgcn_s_setprio(0);

  // ---- prologue: stage B(0), A(0), B(1)  [order fixed for vmcnt math] ----
  STAGE_HALF(gB, 0,   0, 32768) STAGE_HALF(gB, 0,   1, 32768)
  STAGE_HALF(gA, 0,   0, 0)     STAGE_HALF(gA, 0,   1, 0)
  STAGE_HALF(gB, 64,  0, 49152) STAGE_HALF(gB, 64,  1, 49152)

  // ---- main loop: 5 iterations, each consumes K-tiles (2it, 2it+1) ----
  for (int it = 0; it < 5; ++it) {
    const int kb = it * 128;
    // P0
    VMW("4") BARR
    LDB8(0) LDA4(0, 0, 1)
    STAGE_HALF(gA, kb + 64, 0, 16384)
    SYNC_MFMA MFMA_PAIR(0, 1) END_MFMA
    // P1
    BARR
    LDA4(0, 2, 3)
    STAGE_HALF(gA, kb + 64, 1, 16384)
    SYNC_MFMA MFMA_PAIR(2, 3) END_MFMA
    // P2
    BARR
    LDA4(0, 4, 5)
    STAGE_HALF(gB, kb + 128, 0, 32768)
    SYNC_MFMA MFMA_PAIR(4, 5) END_MFMA
    // P3
    BARR
    LDA4(0, 6, 7)
    STAGE_HALF(gB, kb + 128, 1, 32768)
    SYNC_MFMA MFMA_PAIR(6, 7) END_MFMA
    // P4
    VMW("4") BARR
    LDB8(1) LDA4(1, 0, 1)
    STAGE_HALF(gA, kb + 128, 0, 0)
    SYNC_MFMA MFMA_PAIR(0, 1) END_MFMA
    // P5
    BARR
    LDA4(1, 2, 3)
    STAGE_HALF(gA, kb + 128, 1, 0)
    SYNC_MFMA MFMA_PAIR(2, 3) END_MFMA
    // P6
    BARR
    LDA4(1, 4, 5)
    STAGE_HALF(gB, kb + 192, 0, 49152)
    SYNC_MFMA MFMA_PAIR(4, 5) END_MFMA
    // P7
    BARR
    LDA4(1, 6, 7)
    STAGE_HALF(gB, kb + 192, 1, 49152)
    SYNC_MFMA MFMA_PAIR(6, 7) END_MFMA
  }

  // ---- epilogue: consume K-tiles 10 (slot0), 11 (slot1) ----
  // P0
  VMW("4") BARR
  LDB8(0) LDA4(0, 0, 1)
  STAGE_HALF(gA, 704, 0, 16384)          // Alo(11)
  SYNC_MFMA MFMA_PAIR(0, 1) END_MFMA
  // P1
  BARR
  LDA4(0, 2, 3)
  STAGE_HALF(gA, 704, 1, 16384)          // Ahi(11)
  SYNC_MFMA MFMA_PAIR(2, 3) END_MFMA
  // P2
  BARR
  LDA4(0, 4, 5)
  SYNC_MFMA MFMA_PAIR(4, 5) END_MFMA
  // P3
  BARR
  LDA4(0, 6, 7)
  SYNC_MFMA MFMA_PAIR(6, 7) END_MFMA
  // P4
  VMW("0") BARR
  LDB8(1) LDA4(1, 0, 1)
  SYNC_MFMA MFMA_PAIR(0, 1) END_MFMA
  // P5
  BARR
  LDA4(1, 2, 3)
  SYNC_MFMA MFMA_PAIR(2, 3) END_MFMA
  // P6
  BARR
  LDA4(1, 4, 5)
  SYNC_MFMA MFMA_PAIR(4, 5) END_MFMA
  // P7
  BARR
  LDA4(1, 6, 7)
  SYNC_MFMA MFMA_PAIR(6, 7) END_MFMA

#undef STAGE_HALF
#undef LDA
#undef LDB
#undef MM4
#undef MFMA_PAIR
#undef LDB8
#undef LDA4
#undef BARR
#undef VMW
#undef SYNC_MFMA
#undef END_MFMA

  // epilogue (swapped layout): lane holds C[row = ..+lo4][col = ..+hi4*4+j]
#pragma unroll
  for (int m = 0; m < 8; ++m) {
    const int r = row0 + wr * 128 + m * 16 + lo4;
    if (r < Mloc) {
#pragma unroll
      for (int n = 0; n < 4; ++n) {
        const int cb = col0 + wc * 64 + n * 16 + hi4 * 4;
        f32x4 v = acc[m][n];
        if (is2) {
          *reinterpret_cast<f32x4*>(C2 + (size_t)r * N + cb) = v;
        } else if constexpr (OUT_BF16) {
          union { __hip_bfloat16 h[4]; uint2 u; } p;
          p.h[0] = __float2bfloat16(v[0]); p.h[1] = __float2bfloat16(v[1]);
          p.h[2] = __float2bfloat16(v[2]); p.h[3] = __float2bfloat16(v[3]);
          *reinterpret_cast<uint2*>((__hip_bfloat16*)Cv + (size_t)r * N + cb) = p.u;
        } else {
          __builtin_nontemporal_store(
              v, reinterpret_cast<f32x4*>((float*)Cv + (size_t)r * N + cb));
        }
      }
    }
  }
}

// ---------------------------------------------------------------------------
// attn: one block per (slot_local, w, h), 120 threads = 30 qi x 4 part.
// ---------------------------------------------------------------------------
__global__ __launch_bounds__(128) void attn_kernel(const float* __restrict__ Qs,
    const __hip_bfloat16* __restrict__ Y, __hip_bfloat16* __restrict__ ctx, int s0) {
  int blk = blockIdx.x;
  int h  = blk % NH;
  int w  = (blk / NH) % WNUM;
  int sl = blk / (NH * WNUM);
  int b  = (s0 + sl) & 15;          // batch index (doc-independent Q)

  __shared__ float Dl[WINSZ][DH_];

  const __hip_bfloat16* Yb = Y + ((size_t)(sl * LD + w * WINSZ)) * DIM + h * (WINSZ * DH_);
  const float* Qb = Qs + (size_t)b * (LQ * DIM) + h * (LQ * DH_);

  int tid = threadIdx.x;
  int qi = tid >> 2, part = tid & 3;

  if (tid < 88) {
    uint4 raw = *reinterpret_cast<const uint4*>(Yb + tid * 8);
    const __hip_bfloat16* hp = reinterpret_cast<const __hip_bfloat16*>(&raw);
    float* dst = &Dl[0][0] + tid * 8;
#pragma unroll
    for (int j = 0; j < 8; ++j) dst[j] = __bfloat162float(hp[j]);
  }

  float4 qreg[4];
#pragma unroll
  for (int j = 0; j < 4; ++j)
    qreg[j] = *reinterpret_cast<const float4*>(Qb + qi * DH_ + part * 16 + j * 4);
  __syncthreads();

  float dot[WINSZ];
#pragma unroll
  for (int k = 0; k < WINSZ; ++k) {
    const float4* dp = reinterpret_cast<const float4*>(&Dl[k][part * 16]);
    float s = 0.f;
#pragma unroll
    for (int j = 0; j < 4; ++j) {
      float4 dv = dp[j];
      s += qreg[j].x * dv.x + qreg[j].y * dv.y + qreg[j].z * dv.z + qreg[j].w * dv.w;
    }
    dot[k] = s;
  }
#pragma unroll
  for (int k = 0; k < WINSZ; ++k) {
    dot[k] += __shfl_xor(dot[k], 1);
    dot[k] += __shfl_xor(dot[k], 2);
  }
  float mx = -1e30f;
#pragma unroll
  for (int k = 0; k < WINSZ; ++k) mx = fmaxf(mx, dot[k]);
  float sum = 0.f;
#pragma unroll
  for (int k = 0; k < WINSZ; ++k) { dot[k] = expf(dot[k] - mx); sum += dot[k]; }
  float inv = 1.f / sum;

  float4 o[4] = {};
#pragma unroll
  for (int k = 0; k < WINSZ; ++k) {
    float pk = dot[k];
    const float4* dp = reinterpret_cast<const float4*>(&Dl[k][part * 16]);
#pragma unroll
    for (int j = 0; j < 4; ++j) {
      float4 dv = dp[j];
      o[j].x += pk * dv.x; o[j].y += pk * dv.y;
      o[j].z += pk * dv.z; o[j].w += pk * dv.w;
    }
  }
  union { __hip_bfloat16 hh[16]; uint4 v[2]; } pk;
#pragma unroll
  for (int j = 0; j < 4; ++j) {
    pk.hh[j * 4 + 0] = __float2bfloat16(o[j].x * inv);
    pk.hh[j * 4 + 1] = __float2bfloat16(o[j].y * inv);
    pk.hh[j * 4 + 2] = __float2bfloat16(o[j].z * inv);
    pk.hh[j * 4 + 3] = __float2bfloat16(o[j].w * inv);
  }
  __hip_bfloat16* op = ctx + (size_t)(sl * WNUM + w) * (LQ * DIM)
                     + h * (LQ * DH_) + qi * DH_ + part * 16;
  *reinterpret_cast<uint4*>(op)     = pk.v[0];
  *reinterpret_cast<uint4*>(op + 8) = pk.v[1];
}

// ---------------------------------------------------------------------------
extern "C" void kernel_launch(void* const* d_in, const int* in_sizes, int n_in,
                              void* d_out, int out_size, void* d_ws, size_t ws_size,
                              hipStream_t stream) {
  const int*   q      = (const int*)d_in[0];
  const int*   dpos   = (const int*)d_in[1];
  const int*   dneg   = (const int*)d_in[2];
  const float* qmask  = (const float*)d_in[3];
  const float* dpmask = (const float*)d_in[4];
  const float* dnmask = (const float*)d_in[5];
  const int*   peflag = (const int*)d_in[6];
  const float* emb    = (const float*)d_in[7];
  const float* Wlin   = (const float*)d_in[8];
  const float* Wout   = (const float*)d_in[9];
  float* out = (float*)d_out;

  (void)hipFuncSetAttribute(reinterpret_cast<const void*>(&gemm_mfma<false>),
                            hipFuncAttributeMaxDynamicSharedMemorySize, 131072);
  (void)hipFuncSetAttribute(reinterpret_cast<const void*>(&gemm_mfma<true>),
                            hipFuncAttributeMaxDynamicSharedMemorySize, 131072);

  char* ws = (char*)d_ws;
  size_t off = 0;
  auto alloc = [&](size_t bytes) -> char* {
    char* p = ws + off; off += (bytes + 255) & ~(size_t)255; return p;
  };
  __hip_bfloat16* Xq   = (__hip_bfloat16*)alloc((size_t)512 * DIM * 2);  // 480 rows + tile pad
  float*          Qsc  = (float*)         alloc((size_t)B_ * LQ * DIM * 4);
  __hip_bfloat16* Wl16 = (__hip_bfloat16*)alloc((size_t)DIM * DIM * 2);
  __hip_bfloat16* Wo16 = (__hip_bfloat16*)alloc((size_t)DIM * DIM * 2);
  float*          PE   = (float*)         alloc((size_t)LD * DIM * 4);   // 3.4 MB

  int SC = NSLOT;
  while (SC > 1) {
    size_t need = off
        + ((size_t)SC * LD + 256) * DIM * 2 * 2                 // X + Y
        + ((size_t)SC * WNUM * LQ + 256) * DIM * 2 + (1u << 20);// ctx
    if (need <= ws_size) break;
    SC >>= 1;
  }
  __hip_bfloat16* X   = (__hip_bfloat16*)alloc(((size_t)SC * LD + 256) * DIM * 2);
  __hip_bfloat16* Y   = (__hip_bfloat16*)alloc(((size_t)SC * LD + 256) * DIM * 2);
  __hip_bfloat16* ctx = (__hip_bfloat16*)alloc(((size_t)SC * WNUM * LQ + 256) * DIM * 2);

  wconv_kernel<<<(DIM * DIM / 4 + 255) / 256, 256, 0, stream>>>(Wlin, Wout, Wl16, Wo16);
  pe_kernel<<<(LD * (DIM / 4) + 255) / 256, 256, 0, stream>>>(PE);
  prep_q_kernel<<<(B_ * LQ * (DIM / 4) + 255) / 256, 256, 0, stream>>>(q, qmask, emb, Xq);

  const int tilesX = DIM / 256;                       // 3
  const int qTiles = tilesX * ((B_ * LQ + 255) / 256);// 6 (Q-problem blocks)

  for (int s0 = 0; s0 < NSLOT; s0 += SC) {
    const int rowsX = SC * LD;           // 35200 at SC=32
    const int rowsC = SC * WNUM * LQ;    // 96000 at SC=32
    prep_d_kernel<<<(rowsX * (DIM / 4) + 255) / 256, 256, 0, stream>>>(
        dpos, dneg, dpmask, dnmask, emb, peflag, PE, X, s0, rowsX);
    {
      int tiles1 = tilesX * ((rowsX + 255) / 256);
      int t2 = (s0 == 0) ? qTiles : 0;
      gemm_mfma<true><<<tiles1 + t2, 512, 131072, stream>>>(
          X, Wl16, Y, rowsX, DIM, DIM, tilesX, tiles1, Xq, Qsc, B_ * LQ);
    }
    attn_kernel<<<SC * WNUM * NH, 120, 0, stream>>>(Qsc, Y, ctx, s0);
    {
      int tiles1 = tilesX * ((rowsC + 255) / 256);
      gemm_mfma<false><<<tiles1, 512, 131072, stream>>>(
          ctx, Wo16, out + (size_t)s0 * WNUM * LQ * DIM, rowsC, DIM, DIM,
          tilesX, tiles1, nullptr, nullptr, 0);
    }
  }
}